// Round 10
// baseline (105.814 us; speedup 1.0000x reference)
//
#include <hip/hip_runtime.h>
#include <hip/hip_bf16.h>
#include <stdint.h>

typedef short bf16x8 __attribute__((ext_vector_type(8)));
typedef short short8 __attribute__((ext_vector_type(8)));
typedef float f32x4 __attribute__((ext_vector_type(4)));

#define B_   64
#define NQ   32
#define ND   256
#define DIM  128
#define MT   2          // bq per MFMA group
#define NEG_INF_F (-1.0e9f)
#define VALID_F   (-1.0e8f)

// Single fused kernel, round 9 structure:
// Grid 512 = (bd in 0..63) x (g in 0..7), 512 threads (8 waves), 2 blocks/CU.
// D panel is NEVER staged in LDS: each wave's B-fragments are built directly
// from global f32 into 32 VGPRs (lane (lr,lk) of wave w holds doc rows
// {w*32+ni*16+lr}, features {kk*32+lk*8..+7}; row-norm via 2-step shfl_xor
// over the lk bits). LDS = 16KB Q panel (64 rows, XOR-swizzled) + 4KB reduce.
// Per mm-group (MT=2 bq): stage+normalize 64 q rows into ldsQ, MFMA (wave w
// owns doc cols [w*32,w*32+32)), chamfer shuffle-tree reductions.
// MFMA 16x16x32 bf16: A lane row=l&15, k=(l>>4)*8+j; B lane col=l&15, same k;
// C/D col=l&15, row=(l>>4)*4+reg.
// Masking is ARITHMETIC: tok = acc + qneg[t] + dneg[s], {0,-1e9} addends.
// Mask quirk: pair (bq,bd) gated by qm[bq,t] && dm[bq,s] (doc mask via QUERY
// batch); doc embeddings themselves zeroed by dm[bd,s] in the B-frag scale.
__global__ __launch_bounds__(512, 4) void chamfer_one(
    const float* __restrict__ q,
    const int* __restrict__ qmask,
    const float* __restrict__ d,
    const int* __restrict__ dmask,
    float* __restrict__ out)
{
    __shared__ __hip_bfloat16 ldsQ[2 * NQ * DIM];    // 16 KB (one mm-group of Q)
    __shared__ float s_cmax[MT][ND];                 // 2 KB
    __shared__ float s_rmaxT[MT][NQ][8];             // 2 KB

    const int bd  = blockIdx.x & 63;
    const int g   = blockIdx.x >> 6;   // 0..7
    const int tid = threadIdx.x;
    const int w   = tid >> 6;          // wave 0..7
    const int l   = tid & 63;
    const int lr  = l & 15;
    const int lk  = l >> 4;
    const int grp = tid >> 4;          // 16-lane group 0..31
    const int sub = tid & 15;

    const float* Dsrc = d + (size_t)bd * ND * DIM;

    // ---- issue ALL D loads back-to-back: 16 dwordx4 (2 rows x 4 kk-chunks) ----
    float4 dv[2][4][2];
    int    dmk[2];
    #pragma unroll
    for (int ni = 0; ni < 2; ++ni) {
        const int r = w * 32 + ni * 16 + lr;
        #pragma unroll
        for (int kk = 0; kk < 4; ++kk) {
            const float* p = Dsrc + r * DIM + kk * 32 + lk * 8;
            dv[ni][kk][0] = *reinterpret_cast<const float4*>(p);
            dv[ni][kk][1] = *reinterpret_cast<const float4*>(p + 4);
        }
        dmk[ni] = dmask[bd * ND + r];
    }

    // ---- prefetch mm=0's Q loads (overlap with D normalize) ----
    float4 qva[2], qvb[2];
    int    qmk[2];
    {
        const float* Qsrc = q + (size_t)(g * 8) * NQ * DIM;
        #pragma unroll
        for (int it = 0; it < 2; ++it) {
            const int row = it * 32 + grp;        // 0..63
            qva[it] = *reinterpret_cast<const float4*>(Qsrc + row * DIM + sub * 8);
            qvb[it] = *reinterpret_cast<const float4*>(Qsrc + row * DIM + sub * 8 + 4);
            qmk[it] = qmask[(g * 8) * NQ + row];
        }
    }

    // ---- build B-fragments in registers (norm via 2-step shuffle over lk) ----
    bf16x8 Bfr[4][2];   // [kk][ni]
    #pragma unroll
    for (int ni = 0; ni < 2; ++ni) {
        float ss = 0.0f;
        #pragma unroll
        for (int kk = 0; kk < 4; ++kk) {
            const float4 a = dv[ni][kk][0], b = dv[ni][kk][1];
            ss += a.x*a.x + a.y*a.y + a.z*a.z + a.w*a.w
                + b.x*b.x + b.y*b.y + b.z*b.z + b.w*b.w;
        }
        ss += __shfl_xor(ss, 16);
        ss += __shfl_xor(ss, 32);
        const float scale = dmk[ni] ? (1.0f / fmaxf(sqrtf(ss), 1e-12f)) : 0.0f;
        #pragma unroll
        for (int kk = 0; kk < 4; ++kk) {
            const float f[8] = {dv[ni][kk][0].x, dv[ni][kk][0].y, dv[ni][kk][0].z, dv[ni][kk][0].w,
                                dv[ni][kk][1].x, dv[ni][kk][1].y, dv[ni][kk][1].z, dv[ni][kk][1].w};
            short8 o;
            #pragma unroll
            for (int j = 0; j < 8; ++j) {
                __hip_bfloat16 h = __float2bfloat16(f[j] * scale);
                o[j] = *reinterpret_cast<short*>(&h);
            }
            Bfr[kk][ni] = o;
        }
    }

    // ---- 4 mm-groups of MT=2 bq ----
    #pragma unroll 1
    for (int mm = 0; mm < 4; ++mm) {
        const int bq0 = g * 8 + mm * MT;

        if (mm > 0) {   // mm=0's loads already in flight
            const float* Qsrc = q + (size_t)bq0 * NQ * DIM;
            #pragma unroll
            for (int it = 0; it < 2; ++it) {
                const int row = it * 32 + grp;
                qva[it] = *reinterpret_cast<const float4*>(Qsrc + row * DIM + sub * 8);
                qvb[it] = *reinterpret_cast<const float4*>(Qsrc + row * DIM + sub * 8 + 4);
                qmk[it] = qmask[bq0 * NQ + row];
            }
        }

        // normalize 64 q rows into ldsQ (swizzled)
        #pragma unroll
        for (int it = 0; it < 2; ++it) {
            const int row = it * 32 + grp;        // 0..63
            const float4 v0 = qva[it], v1 = qvb[it];
            float ss = v0.x*v0.x + v0.y*v0.y + v0.z*v0.z + v0.w*v0.w
                     + v1.x*v1.x + v1.y*v1.y + v1.z*v1.z + v1.w*v1.w;
            #pragma unroll
            for (int off = 1; off <= 8; off <<= 1) ss += __shfl_xor(ss, off);
            const float scale = qmk[it] ? (1.0f / fmaxf(sqrtf(ss), 1e-12f)) : 0.0f;
            short8 o;
            const float f[8] = {v0.x, v0.y, v0.z, v0.w, v1.x, v1.y, v1.z, v1.w};
            #pragma unroll
            for (int j = 0; j < 8; ++j) {
                __hip_bfloat16 b = __float2bfloat16(f[j] * scale);
                o[j] = *reinterpret_cast<short*>(&b);
            }
            *reinterpret_cast<short8*>((char*)&ldsQ[0] + row * 256 + ((sub ^ (row & 7)) << 4)) = o;
        }

        // gate masks -> NEG_INF addends (doc-gate indexed by bq — reference quirk)
        float qneg[MT][2][4];
        float dneg[MT][2];
        #pragma unroll
        for (int m = 0; m < MT; ++m) {
            #pragma unroll
            for (int mi = 0; mi < 2; ++mi) {
                const int4 qi = *reinterpret_cast<const int4*>(&qmask[(bq0 + m) * NQ + mi * 16 + lk * 4]);
                qneg[m][mi][0] = qi.x ? 0.0f : NEG_INF_F;
                qneg[m][mi][1] = qi.y ? 0.0f : NEG_INF_F;
                qneg[m][mi][2] = qi.z ? 0.0f : NEG_INF_F;
                qneg[m][mi][3] = qi.w ? 0.0f : NEG_INF_F;
            }
            #pragma unroll
            for (int ni = 0; ni < 2; ++ni)
                dneg[m][ni] = dmask[(bq0 + m) * ND + w * 32 + ni * 16 + lr] ? 0.0f : NEG_INF_F;
        }

        __syncthreads();   // ldsQ ready; prev tail done with s_*

        // MFMA: wave w owns doc cols [w*32, w*32+32); A from swizzled LDS, B in regs
        f32x4 acc[MT][2][2] = {};
        #pragma unroll
        for (int kk = 0; kk < 4; ++kk) {
            const int cL = kk * 4 + lk;               // logical 16B chunk 0..15
            #pragma unroll
            for (int m = 0; m < MT; ++m) {
                #pragma unroll
                for (int mi = 0; mi < 2; ++mi) {
                    const int rowq = m * NQ + mi * 16 + lr;
                    const bf16x8 a = *reinterpret_cast<const bf16x8*>(
                        (const char*)&ldsQ[0] + rowq * 256 + ((cL ^ (rowq & 7)) << 4));
                    #pragma unroll
                    for (int ni = 0; ni < 2; ++ni)
                        acc[m][mi][ni] = __builtin_amdgcn_mfma_f32_16x16x32_bf16(a, Bfr[kk][ni], acc[m][mi][ni], 0, 0, 0);
                }
            }
        }

        // per-wave partial maxes (arithmetic masking) -> LDS
        #pragma unroll
        for (int m = 0; m < MT; ++m) {
            float rmax[2][4];
            float cmax[2] = {NEG_INF_F, NEG_INF_F};
            #pragma unroll
            for (int mi = 0; mi < 2; ++mi) {
                #pragma unroll
                for (int r = 0; r < 4; ++r) {
                    const float t0 = acc[m][mi][0][r] + (qneg[m][mi][r] + dneg[m][0]);
                    const float t1 = acc[m][mi][1][r] + (qneg[m][mi][r] + dneg[m][1]);
                    rmax[mi][r] = fmaxf(t0, t1);
                    cmax[0] = fmaxf(cmax[0], t0);
                    cmax[1] = fmaxf(cmax[1], t1);
                }
            }
            // col max over all 32 rows (lanes differing in lk)
            #pragma unroll
            for (int ni = 0; ni < 2; ++ni) {
                cmax[ni] = fmaxf(cmax[ni], __shfl_xor(cmax[ni], 16));
                cmax[ni] = fmaxf(cmax[ni], __shfl_xor(cmax[ni], 32));
            }
            if (lk == 0) {
                #pragma unroll
                for (int ni = 0; ni < 2; ++ni)
                    s_cmax[m][w * 32 + ni * 16 + lr] = cmax[ni];
            }
            // row max over this wave's 32 cols (lanes differing in lr)
            #pragma unroll
            for (int mi = 0; mi < 2; ++mi)
                #pragma unroll
                for (int r = 0; r < 4; ++r) {
                    #pragma unroll
                    for (int off = 1; off <= 8; off <<= 1)
                        rmax[mi][r] = fmaxf(rmax[mi][r], __shfl_xor(rmax[mi][r], off));
                }
            if (lr == 0) {
                #pragma unroll
                for (int mi = 0; mi < 2; ++mi)
                    #pragma unroll
                    for (int r = 0; r < 4; ++r)
                        s_rmaxT[m][mi * 16 + lk * 4 + r][w] = rmax[mi][r];
            }
        }
        __syncthreads();

        // tail: waves 0..1 finish bq = bq0 + w (others fall through to next stageQ)
        if (w < MT) {
            const int m = w;
            const float4 cm = *reinterpret_cast<const float4*>(&s_cmax[m][l * 4]);
            float sd = 0.0f, cd = 0.0f;
            if (cm.x > VALID_F) { sd += cm.x; cd += 1.0f; }
            if (cm.y > VALID_F) { sd += cm.y; cd += 1.0f; }
            if (cm.z > VALID_F) { sd += cm.z; cd += 1.0f; }
            if (cm.w > VALID_F) { sd += cm.w; cd += 1.0f; }
            float sq = 0.0f, cq = 0.0f;
            if (l < NQ) {
                const float4 a = *reinterpret_cast<const float4*>(&s_rmaxT[m][l][0]);
                const float4 b = *reinterpret_cast<const float4*>(&s_rmaxT[m][l][4]);
                const float v = fmaxf(fmaxf(fmaxf(a.x, a.y), fmaxf(a.z, a.w)),
                                      fmaxf(fmaxf(b.x, b.y), fmaxf(b.z, b.w)));
                if (v > VALID_F) { sq = v; cq = 1.0f; }
            }
            #pragma unroll
            for (int off = 1; off <= 32; off <<= 1) {
                sd += __shfl_xor(sd, off);
                cd += __shfl_xor(cd, off);
                sq += __shfl_xor(sq, off);
                cq += __shfl_xor(cq, off);
            }
            if (l == 0) {
                const float q2d = sq / fmaxf(cq, 1.0f);
                const float d2q = sd / fmaxf(cd, 1.0f);
                out[(bq0 + m) * B_ + bd] = 0.5f * (q2d + d2q);
            }
        }
        // no barrier: next stageQ writes ldsQ only after this iteration's 2nd
        // barrier (all MFMA reads done); tail reads s_* which stageQ doesn't touch.
    }
}

extern "C" void kernel_launch(void* const* d_in, const int* in_sizes, int n_in,
                              void* d_out, int out_size, void* d_ws, size_t ws_size,
                              hipStream_t stream) {
    const float* q  = (const float*)d_in[0];   // [64][32][128] f32
    const int*   qm = (const int*)d_in[1];     // [64][32] i32
    const float* d  = (const float*)d_in[2];   // [64][256][128] f32
    const int*   dm = (const int*)d_in[3];     // [64][256] i32
    float* out = (float*)d_out;                // [64][64] f32

    chamfer_one<<<B_ * 8, 512, 0, stream>>>(q, qm, d, dm, out);
}